// Round 3
// baseline (349.182 us; speedup 1.0000x reference)
//
#include <hip/hip_runtime.h>

// ---------------------------------------------------------------------------
// AttentionHead: B=4, C=256, N=4096, QK=64. Column-softmax attention.
//   proj:   Qt=(WQ x+bQ+PE)*0.125*log2e, Kt=WK x+bK+PE, Vc=WV x+bV  (bf16)
//   colsum: s_part[ic][b][j] = sum_{i in chunk ic} 2^(Qt_i . Kt_j)   (4 chunks)
//   attn:   lrs_j = -log2(sum_ic s_part);  Opart[jc] = sum_{j in chunk jc}
//           2^(S_ij + lrs_j) * V   (bf16 partials, jc = 0,1)
//   mlp:    att = Opart0+Opart1 (LDS) -> mish(W1 att+b1) (LDS) -> W2 .. +b2+x
// All GEMMs bf16 MFMA 16x16x32. Weights converted fp32->bf16 per-use (L2-hot).
// Occupancy: every grid >= 1024 blocks (4 blocks/CU) except attn (512, 2/CU).
// Workspace: 29,622,272 bytes.
// ---------------------------------------------------------------------------

typedef unsigned short u16;
typedef __attribute__((ext_vector_type(8))) unsigned short ushort8;
typedef __attribute__((ext_vector_type(8))) __bf16 bf16x8;
typedef __attribute__((ext_vector_type(4))) float f32x4;

#define MFMA16(a, b, c) __builtin_amdgcn_mfma_f32_16x16x32_bf16((a), (b), (c), 0, 0, 0)

#define QSCALE 0.18033688011112042f  // 0.125 * log2(e)

__device__ __forceinline__ u16 f2bf(float f) {  // round-to-nearest-even
  unsigned int u = __builtin_bit_cast(unsigned int, f);
  u += 0x7FFFu + ((u >> 16) & 1u);
  return (u16)(u >> 16);
}
__device__ __forceinline__ u16 f2bft(float f) {  // truncate (1 op)
  return (u16)(__builtin_bit_cast(unsigned int, f) >> 16);
}
__device__ __forceinline__ float bf2f(u16 u) {
  return __builtin_bit_cast(float, ((unsigned int)u) << 16);
}
__device__ __forceinline__ bf16x8 ld8(const u16* p) {
  return __builtin_bit_cast(bf16x8, *reinterpret_cast<const ushort8*>(p));
}
__device__ __forceinline__ bf16x8 ld8f(const float* p) {  // 8 fp32 -> bf16x8
  const float4* q = reinterpret_cast<const float4*>(p);
  float4 a = q[0], b = q[1];
  ushort8 r;
  r[0] = f2bf(a.x); r[1] = f2bf(a.y); r[2] = f2bf(a.z); r[3] = f2bf(a.w);
  r[4] = f2bf(b.x); r[5] = f2bf(b.y); r[6] = f2bf(b.z); r[7] = f2bf(b.w);
  return __builtin_bit_cast(bf16x8, r);
}
__device__ __forceinline__ f32x4 fz4() {
  f32x4 z = {0.f, 0.f, 0.f, 0.f};
  return z;
}

// ---- fused QKV projection, straight from x fp32 [b][c][pos] ---------------
// i-tile = 16 pos. Q/K: D[pos][o]; V: D[o][pos]. Grid (256, 4).
__global__ __launch_bounds__(256, 4) void k_proj(
    const float* __restrict__ x, const float* __restrict__ WQ,
    const float* __restrict__ bQ, const float* __restrict__ WK,
    const float* __restrict__ bK, const float* __restrict__ WV,
    const float* __restrict__ bV, const float* __restrict__ PE,
    u16* __restrict__ Qt, u16* __restrict__ Kt, u16* __restrict__ Vc) {
  int n0 = blockIdx.x * 16, b = blockIdx.y;
  int lane = threadIdx.x & 63, wid = threadIdx.x >> 6;
  int l15 = lane & 15, g = lane >> 4;
  const float* xb = x + (size_t)b * 1048576 + n0 + l15;  // + c*4096

  f32x4 aq = fz4(), ak = fz4(), av[4];
#pragma unroll
  for (int m = 0; m < 4; ++m) av[m] = fz4();

  for (int kk = 0; kk < 8; ++kk) {
    int c0 = kk * 32 + 8 * g;
    ushort8 xr;
#pragma unroll
    for (int e = 0; e < 8; ++e) xr[e] = f2bf(xb[(size_t)(c0 + e) * 4096]);
    bf16x8 xa = __builtin_bit_cast(bf16x8, xr);
    bf16x8 fq = ld8f(WQ + (16 * wid + l15) * 256 + c0);
    bf16x8 fk = ld8f(WK + (16 * wid + l15) * 256 + c0);
    aq = MFMA16(xa, fq, aq);
    ak = MFMA16(xa, fk, ak);
#pragma unroll
    for (int m = 0; m < 4; ++m) {
      bf16x8 fv = ld8f(WV + (64 * wid + 16 * m + l15) * 256 + c0);
      av[m] = MFMA16(fv, xa, av[m]);
    }
  }
  // Q/K epilogue: D col=o=16wid+l15, row=pos_local=4g+r
  int o = 16 * wid + l15;
#pragma unroll
  for (int r = 0; r < 4; ++r) {
    int pos = n0 + 4 * g + r;
    float pe = PE[o * 4096 + pos];
    Qt[((size_t)b * 4096 + pos) * 64 + o] = f2bf((aq[r] + bQ[o] + pe) * QSCALE);
    Kt[((size_t)b * 4096 + pos) * 64 + o] = f2bf(ak[r] + bK[o] + pe);
  }
  // V epilogue: D col=pos=l15, row=o_local=4g+r
#pragma unroll
  for (int m = 0; m < 4; ++m)
#pragma unroll
    for (int r = 0; r < 4; ++r) {
      int ov = 64 * wid + 16 * m + 4 * g + r;
      int pos = n0 + l15;
      Vc[((size_t)b * 256 + ov) * 4096 + pos] = f2bf(av[m][r] + bV[ov]);
    }
}

// ---- pass 1: partial column sums of 2^S over 4 i-chunks -------------------
// Grid (64 j-tiles, 4 i-chunks, 4 b). sp[(ic*4+b)*4096 + j].
__global__ __launch_bounds__(256, 4) void k_colsum(const u16* __restrict__ Qt,
                                                   const u16* __restrict__ Kt,
                                                   float* __restrict__ sp) {
  int j0 = blockIdx.x * 64, ic = blockIdx.y, b = blockIdx.z;
  int lane = threadIdx.x & 63, wid = threadIdx.x >> 6;
  int l15 = lane & 15, g = lane >> 4;
  const u16* qb = Qt + (size_t)b * 262144;
  const u16* kb = Kt + (size_t)b * 262144;
  int j = j0 + 16 * wid + l15;
  bf16x8 fk0 = ld8(kb + j * 64 + 8 * g);
  bf16x8 fk1 = ld8(kb + j * 64 + 32 + 8 * g);
  float part = 0.f;
  for (int i0 = ic * 1024; i0 < ic * 1024 + 1024; i0 += 64) {
    f32x4 acc[4];
#pragma unroll
    for (int m = 0; m < 4; ++m) {
      const u16* qr = qb + (i0 + 16 * m + l15) * 64;
      acc[m] = fz4();
      acc[m] = MFMA16(ld8(qr + 8 * g), fk0, acc[m]);
      acc[m] = MFMA16(ld8(qr + 32 + 8 * g), fk1, acc[m]);
    }
#pragma unroll
    for (int m = 0; m < 4; ++m)
#pragma unroll
      for (int r = 0; r < 4; ++r) part += exp2f(acc[m][r]);
  }
  part += __shfl_xor(part, 16);
  part += __shfl_xor(part, 32);
  if (g == 0) sp[((size_t)ic * 4 + b) * 4096 + j] = part;
}

// ---- pass 2: partial O over 2 j-chunks ------------------------------------
// Grid (64 i-tiles, 2 j-chunks, 4 b). Opart[(jc*4+b)][pos][c] bf16.
__global__ __launch_bounds__(256, 3) void k_attn(
    const u16* __restrict__ Qt, const u16* __restrict__ Kt,
    const u16* __restrict__ Vc, const float* __restrict__ sp,
    u16* __restrict__ Op) {
  __shared__ u16 P[64][72];
  __shared__ float lrsL[2048];
  int i0 = blockIdx.x * 64, jc = blockIdx.y, b = blockIdx.z;
  int t = threadIdx.x, lane = t & 63, wid = t >> 6;
  int l15 = lane & 15, g = lane >> 4;
  const u16* qb = Qt + (size_t)b * 262144;
  const u16* kb = Kt + (size_t)b * 262144;
  const u16* vb = Vc + (size_t)b * 1048576;

  // preamble: lrs_j = -log2(sum of 4 partial column sums) for this j-chunk
#pragma unroll
  for (int q = 0; q < 8; ++q) {
    int jl = q * 256 + t;
    size_t base = (size_t)b * 4096 + jc * 2048 + jl;
    float s = sp[base] + sp[base + 16384] + sp[base + 32768] + sp[base + 49152];
    lrsL[jl] = -log2f(s);
  }
  __syncthreads();

  bf16x8 aq[4][2];
#pragma unroll
  for (int m = 0; m < 4; ++m)
#pragma unroll
    for (int h = 0; h < 2; ++h)
      aq[m][h] = ld8(qb + (i0 + 16 * m + l15) * 64 + h * 32 + 8 * g);

  f32x4 oacc[4][4];
#pragma unroll
  for (int m = 0; m < 4; ++m)
#pragma unroll
    for (int n = 0; n < 4; ++n) oacc[m][n] = fz4();

  for (int j0l = 0; j0l < 2048; j0l += 64) {
    int jg = jc * 2048 + j0l;
    const u16* kr = kb + (size_t)(jg + 16 * wid + l15) * 64;
    bf16x8 fk0 = ld8(kr + 8 * g);
    bf16x8 fk1 = ld8(kr + 32 + 8 * g);
    float lr = lrsL[j0l + 16 * wid + l15];
    f32x4 s[4];
#pragma unroll
    for (int m = 0; m < 4; ++m) {
      s[m] = fz4();
      s[m] = MFMA16(aq[m][0], fk0, s[m]);
      s[m] = MFMA16(aq[m][1], fk1, s[m]);
    }
#pragma unroll
    for (int m = 0; m < 4; ++m)
#pragma unroll
      for (int r = 0; r < 4; ++r)
        P[16 * m + 4 * g + r][16 * wid + l15] = f2bft(exp2f(s[m][r] + lr));
    __syncthreads();
#pragma unroll
    for (int h = 0; h < 2; ++h) {
      bf16x8 ap[4];
#pragma unroll
      for (int m = 0; m < 4; ++m) ap[m] = ld8(&P[16 * m + l15][h * 32 + 8 * g]);
#pragma unroll
      for (int n = 0; n < 4; ++n) {
        bf16x8 fv = ld8(vb + (size_t)(64 * wid + 16 * n + l15) * 4096 + jg + h * 32 + 8 * g);
#pragma unroll
        for (int m = 0; m < 4; ++m) oacc[m][n] = MFMA16(ap[m], fv, oacc[m][n]);
      }
    }
    __syncthreads();
  }
#pragma unroll
  for (int m = 0; m < 4; ++m)
#pragma unroll
    for (int n = 0; n < 4; ++n) {
      int c = 64 * wid + 16 * n + l15;
#pragma unroll
      for (int r = 0; r < 4; ++r) {
        int pos = i0 + 16 * m + 4 * g + r;
        Op[((size_t)(jc * 4 + b) * 4096 + pos) * 256 + c] = f2bf(oacc[m][n][r]);
      }
    }
}

// ---- fused: att = Op0+Op1 -> mish(W1 att + b1) -> W2 .. + b2 + x ----------
// i-tile = 16 pos, grid (256, 4). hdn never leaves LDS.
__global__ __launch_bounds__(256, 4) void k_mlp(
    const u16* __restrict__ Op, const float* __restrict__ W1,
    const float* __restrict__ b1, const float* __restrict__ W2,
    const float* __restrict__ b2, const float* __restrict__ x,
    float* __restrict__ out) {
  __shared__ u16 attS[16][264];
  __shared__ u16 hdnS[16][264];
  int n0 = blockIdx.x * 16, b = blockIdx.y;
  int t = threadIdx.x, lane = t & 63, wid = t >> 6;
  int l15 = lane & 15, g = lane >> 4;

  // stage 1: sum the two bf16 partials into LDS
  {
    int ps = t >> 4, c0 = (t & 15) * 16;
    size_t base0 = ((size_t)b * 4096 + n0 + ps) * 256 + c0;
    size_t base1 = ((size_t)(4 + b) * 4096 + n0 + ps) * 256 + c0;
    ushort8 a0 = *reinterpret_cast<const ushort8*>(Op + base0);
    ushort8 a1 = *reinterpret_cast<const ushort8*>(Op + base0 + 8);
    ushort8 d0 = *reinterpret_cast<const ushort8*>(Op + base1);
    ushort8 d1 = *reinterpret_cast<const ushort8*>(Op + base1 + 8);
    ushort8 r0, r1;
#pragma unroll
    for (int i = 0; i < 8; ++i) {
      r0[i] = f2bf(bf2f(a0[i]) + bf2f(d0[i]));
      r1[i] = f2bf(bf2f(a1[i]) + bf2f(d1[i]));
    }
    *reinterpret_cast<ushort8*>(&attS[ps][c0]) = r0;
    *reinterpret_cast<ushort8*>(&attS[ps][c0 + 8]) = r1;
  }
  __syncthreads();

  // stage 2: hdn = mish(att @ W1^T + b1) -> LDS. D col=h=64wid+16n+l15.
  f32x4 h4[4];
#pragma unroll
  for (int n = 0; n < 4; ++n) h4[n] = fz4();
  for (int kk = 0; kk < 8; ++kk) {
    int c0 = kk * 32 + 8 * g;
    bf16x8 am = ld8(&attS[l15][c0]);
#pragma unroll
    for (int n = 0; n < 4; ++n) {
      bf16x8 bn = ld8f(W1 + (64 * wid + 16 * n + l15) * 256 + c0);
      h4[n] = MFMA16(am, bn, h4[n]);
    }
  }
#pragma unroll
  for (int n = 0; n < 4; ++n) {
    int hh = 64 * wid + 16 * n + l15;
    float bb = b1[hh];
#pragma unroll
    for (int r = 0; r < 4; ++r) {
      float v = h4[n][r] + bb;
      float sp_ = (v > 15.f) ? v : __logf(1.f + __expf(v));
      float e2 = __expf(-2.f * sp_);
      float th = (1.f - e2) / (1.f + e2);
      hdnS[4 * g + r][hh] = f2bf(v * th);
    }
  }
  __syncthreads();

  // stage 3: out = hdn @ W2^T + b2 + x. A=W2 rows (o), B=hdn rows (pos).
  f32x4 acc[4];
#pragma unroll
  for (int m = 0; m < 4; ++m) acc[m] = fz4();
  for (int kk = 0; kk < 8; ++kk) {
    int c0 = kk * 32 + 8 * g;
    bf16x8 bn = ld8(&hdnS[l15][c0]);
#pragma unroll
    for (int m = 0; m < 4; ++m) {
      bf16x8 am = ld8f(W2 + (64 * wid + 16 * m + l15) * 256 + c0);
      acc[m] = MFMA16(am, bn, acc[m]);
    }
  }
#pragma unroll
  for (int m = 0; m < 4; ++m)
#pragma unroll
    for (int r = 0; r < 4; ++r) {
      int o = 64 * wid + 16 * m + 4 * g + r;
      int pos = n0 + l15;
      size_t idx = ((size_t)b * 256 + o) * 4096 + pos;
      out[idx] = acc[m][r] + b2[o] + x[idx];
    }
}

// ---- workspace layout (bytes) ---------------------------------------------
#define WS_QT 0u          //  2,097,152  Qt [4][4096][64]  bf16 (pre-scaled)
#define WS_KT 2097152u    //  2,097,152  Kt [4][4096][64]  bf16
#define WS_VC 4194304u    //  8,388,608  Vc [4][256][4096] bf16
#define WS_SP 12582912u   //    262,144  sp [4 ic][4 b][4096] fp32
#define WS_OP 12845056u   // 16,777,216  Op [2 jc][4 b][4096][256] bf16
                          // end: 29,622,272

extern "C" void kernel_launch(void* const* d_in, const int* in_sizes, int n_in,
                              void* d_out, int out_size, void* d_ws, size_t ws_size,
                              hipStream_t stream) {
  (void)in_sizes; (void)n_in; (void)out_size; (void)ws_size;
  const float* x  = (const float*)d_in[0];
  const float* WQ = (const float*)d_in[1];
  const float* bQ = (const float*)d_in[2];
  const float* WK = (const float*)d_in[3];
  const float* bK = (const float*)d_in[4];
  const float* WV = (const float*)d_in[5];
  const float* bV = (const float*)d_in[6];
  const float* PE = (const float*)d_in[7];
  const float* W1 = (const float*)d_in[8];
  const float* b1 = (const float*)d_in[9];
  const float* W2 = (const float*)d_in[10];
  const float* b2 = (const float*)d_in[11];
  float* out = (float*)d_out;
  char* ws = (char*)d_ws;

  u16* Qt   = (u16*)(ws + WS_QT);
  u16* Kt   = (u16*)(ws + WS_KT);
  u16* Vc   = (u16*)(ws + WS_VC);
  float* sp = (float*)(ws + WS_SP);
  u16* Op   = (u16*)(ws + WS_OP);

  k_proj<<<dim3(256, 4), 256, 0, stream>>>(x, WQ, bQ, WK, bK, WV, bV, PE, Qt, Kt, Vc);
  k_colsum<<<dim3(64, 4, 4), 256, 0, stream>>>(Qt, Kt, sp);
  k_attn<<<dim3(64, 2, 4), 256, 0, stream>>>(Qt, Kt, Vc, sp, Op);
  k_mlp<<<dim3(256, 4), 256, 0, stream>>>(Op, W1, b1, W2, b2, x, out);
}

// Round 4
// 335.413 us; speedup vs baseline: 1.0411x; 1.0411x over previous
//
#include <hip/hip_runtime.h>

// ---------------------------------------------------------------------------
// AttentionHead: B=4, C=256, N=4096, QK=64. Column-softmax attention.
// 5 kernels: convert (w->bf16), proj (QKV), colsum (partial 2^S col sums),
// attn (P=2^(S+lrs) dbuf-LDS -> PV, channel-split, XCD-pinned), mlp (fused).
// Workspace: 21,692,416 bytes.
// ---------------------------------------------------------------------------

typedef unsigned short u16;
typedef unsigned int u32;
typedef __attribute__((ext_vector_type(2))) unsigned int u32x2;
typedef __attribute__((ext_vector_type(8))) unsigned short ushort8;
typedef __attribute__((ext_vector_type(8))) __bf16 bf16x8;
typedef __attribute__((ext_vector_type(4))) float f32x4;

#define MFMA16(a, b, c) __builtin_amdgcn_mfma_f32_16x16x32_bf16((a), (b), (c), 0, 0, 0)
#define QSCALE 0.18033688011112042f  // 0.125 * log2(e)

__device__ __forceinline__ u16 f2bf(float f) {  // round-to-nearest-even
  u32 u = __builtin_bit_cast(u32, f);
  u += 0x7FFFu + ((u >> 16) & 1u);
  return (u16)(u >> 16);
}
__device__ __forceinline__ u32 pack2(float lo, float hi) {  // 2 bf16 (trunc)
  u32 a = __builtin_bit_cast(u32, lo), b = __builtin_bit_cast(u32, hi);
  return (a >> 16) | (b & 0xffff0000u);
}
__device__ __forceinline__ float bf2f(u16 u) {
  return __builtin_bit_cast(float, ((u32)u) << 16);
}
__device__ __forceinline__ bf16x8 ld8(const u16* p) {
  return __builtin_bit_cast(bf16x8, *reinterpret_cast<const ushort8*>(p));
}
__device__ __forceinline__ f32x4 fz4() {
  f32x4 z = {0.f, 0.f, 0.f, 0.f};
  return z;
}

// ---- convert all weight matrices fp32 -> bf16 -----------------------------
__global__ __launch_bounds__(256) void k_convert(
    const float* __restrict__ wq, const float* __restrict__ wk,
    const float* __restrict__ wv, const float* __restrict__ w1,
    const float* __restrict__ w2, u16* __restrict__ dq, u16* __restrict__ dk,
    u16* __restrict__ dv, u16* __restrict__ d1, u16* __restrict__ d2) {
  int i = blockIdx.x * 256 + threadIdx.x;
  if (i < 16384)       dq[i]          = f2bf(wq[i]);
  else if (i < 32768)  dk[i - 16384]  = f2bf(wk[i - 16384]);
  else if (i < 98304)  dv[i - 32768]  = f2bf(wv[i - 32768]);
  else if (i < 163840) d1[i - 98304]  = f2bf(w1[i - 98304]);
  else                 d2[i - 163840] = f2bf(w2[i - 163840]);
}

// ---- fused QKV projection, gathers x fp32 [b][c][pos] directly ------------
// i-tile = 16 pos. Q/K: D[pos][o]; V: D[o][pos]. Grid 1024 (b = id&3).
__global__ __launch_bounds__(256, 4) void k_proj(
    const float* __restrict__ x, const u16* __restrict__ wq,
    const float* __restrict__ bQ, const u16* __restrict__ wk,
    const float* __restrict__ bK, const u16* __restrict__ wv,
    const float* __restrict__ bV, const float* __restrict__ PE,
    u16* __restrict__ Qt, u16* __restrict__ Kt, u16* __restrict__ Vc) {
  int b = blockIdx.x & 3, n0 = (blockIdx.x >> 2) * 16;
  int lane = threadIdx.x & 63, wid = threadIdx.x >> 6;
  int l15 = lane & 15, g = lane >> 4;
  const float* xb = x + (size_t)b * 1048576 + n0 + l15;  // + c*4096

  f32x4 aq = fz4(), ak = fz4(), av[4];
#pragma unroll
  for (int m = 0; m < 4; ++m) av[m] = fz4();

  for (int kk = 0; kk < 8; ++kk) {
    int c0 = kk * 32 + 8 * g;
    ushort8 xr;
#pragma unroll
    for (int e = 0; e < 8; ++e) xr[e] = f2bf(xb[(size_t)(c0 + e) * 4096]);
    bf16x8 xa = __builtin_bit_cast(bf16x8, xr);
    bf16x8 fq = ld8(wq + (16 * wid + l15) * 256 + c0);
    bf16x8 fk = ld8(wk + (16 * wid + l15) * 256 + c0);
    aq = MFMA16(xa, fq, aq);
    ak = MFMA16(xa, fk, ak);
#pragma unroll
    for (int m = 0; m < 4; ++m) {
      bf16x8 fv = ld8(wv + (64 * wid + 16 * m + l15) * 256 + c0);
      av[m] = MFMA16(fv, xa, av[m]);
    }
  }
  int o = 16 * wid + l15;
#pragma unroll
  for (int r = 0; r < 4; ++r) {
    int pos = n0 + 4 * g + r;
    float pe = PE[o * 4096 + pos];
    Qt[((size_t)b * 4096 + pos) * 64 + o] = f2bf((aq[r] + bQ[o] + pe) * QSCALE);
    Kt[((size_t)b * 4096 + pos) * 64 + o] = f2bf(ak[r] + bK[o] + pe);
  }
#pragma unroll
  for (int m = 0; m < 4; ++m)
#pragma unroll
    for (int r = 0; r < 4; ++r) {
      int ov = 64 * wid + 16 * m + 4 * g + r;
      int pos = n0 + l15;
      Vc[((size_t)b * 256 + ov) * 4096 + pos] = f2bf(av[m][r] + bV[ov]);
    }
}

// ---- pass 1: partial column sums of 2^S over 4 i-chunks -------------------
// Grid 1024: combo = id&15 -> (ic,b), jt = id>>4. sp[(ic*4+b)*4096 + j].
__global__ __launch_bounds__(256, 4) void k_colsum(const u16* __restrict__ Qt,
                                                   const u16* __restrict__ Kt,
                                                   float* __restrict__ sp) {
  int combo = blockIdx.x & 15, ic = combo >> 2, b = combo & 3;
  int j0 = (blockIdx.x >> 4) * 64;
  int lane = threadIdx.x & 63, wid = threadIdx.x >> 6;
  int l15 = lane & 15, g = lane >> 4;
  const u16* qb = Qt + (size_t)b * 262144;
  const u16* kb = Kt + (size_t)b * 262144;
  int j = j0 + 16 * wid + l15;
  bf16x8 fk0 = ld8(kb + j * 64 + 8 * g);
  bf16x8 fk1 = ld8(kb + j * 64 + 32 + 8 * g);
  float part = 0.f;
  for (int i0 = ic * 1024; i0 < ic * 1024 + 1024; i0 += 64) {
    f32x4 acc[4];
#pragma unroll
    for (int m = 0; m < 4; ++m) {
      const u16* qr = qb + (i0 + 16 * m + l15) * 64;
      acc[m] = fz4();
      acc[m] = MFMA16(ld8(qr + 8 * g), fk0, acc[m]);
      acc[m] = MFMA16(ld8(qr + 32 + 8 * g), fk1, acc[m]);
    }
#pragma unroll
    for (int m = 0; m < 4; ++m)
#pragma unroll
      for (int r = 0; r < 4; ++r) part += exp2f(acc[m][r]);
  }
  part += __shfl_xor(part, 16);
  part += __shfl_xor(part, 32);
  if (g == 0) sp[((size_t)ic * 4 + b) * 4096 + j] = part;
}

// ---- pass 2: attention, channel-split, double-buffered P, 1 barrier/step --
// Grid 512: id&7 = (cc,b) pins one combo per XCD; it = id>>3.
// S orientation: A=K rows j, B=Q cols i -> lane holds (i=l15, j=4g+r):
// P write = ds_write_b64; PV A-frag read = ds_read_b128.
__global__ __launch_bounds__(256, 2) void k_attn(
    const u16* __restrict__ Qt, const u16* __restrict__ Kt,
    const u16* __restrict__ Vc, const float* __restrict__ sp,
    u16* __restrict__ attT) {
  __shared__ u16 P[2][64][72];
  __shared__ float lrsL[4096];
  int id = blockIdx.x;
  int cc = id & 1, b = (id >> 1) & 3, i0 = (id >> 3) * 64;
  int t = threadIdx.x, lane = t & 63, wid = t >> 6;
  int l15 = lane & 15, g = lane >> 4;
  const u16* qb = Qt + (size_t)b * 262144;
  const u16* kb = Kt + (size_t)b * 262144;
  const u16* vb = Vc + ((size_t)b * 256 + cc * 128) * 4096;

  // lrs_j = -log2(total column sum)
#pragma unroll
  for (int q = 0; q < 16; ++q) {
    int j = q * 256 + t;
    size_t base = (size_t)b * 4096 + j;
    float s = sp[base] + sp[base + 16384] + sp[base + 32768] + sp[base + 49152];
    lrsL[j] = -__log2f(s);
  }

  // Q B-frags for the block's 64 i (held all steps)
  bf16x8 aq[4][2];
#pragma unroll
  for (int m = 0; m < 4; ++m)
#pragma unroll
    for (int h = 0; h < 2; ++h)
      aq[m][h] = ld8(qb + (i0 + 16 * m + l15) * 64 + h * 32 + 8 * g);

  f32x4 oacc[4][2];  // [i-tile m][c-tile n], lane: i=16m+4g+r, c=32wid+16n+l15
#pragma unroll
  for (int m = 0; m < 4; ++m)
#pragma unroll
    for (int n = 0; n < 2; ++n) oacc[m][n] = fz4();

  // K A-frags for step 0 (wave wid owns j-subtile 16*wid)
  const u16* kr0 = kb + (16 * wid + l15) * 64;
  bf16x8 fk0 = ld8(kr0 + 8 * g);
  bf16x8 fk1 = ld8(kr0 + 32 + 8 * g);
  __syncthreads();  // lrsL ready

  // S(0) -> P[0]
  {
    float4 lr = *reinterpret_cast<const float4*>(&lrsL[16 * wid + 4 * g]);
#pragma unroll
    for (int m = 0; m < 4; ++m) {
      f32x4 s = fz4();
      s = MFMA16(fk0, aq[m][0], s);
      s = MFMA16(fk1, aq[m][1], s);
      u32x2 pw = {pack2(exp2f(s[0] + lr.x), exp2f(s[1] + lr.y)),
                  pack2(exp2f(s[2] + lr.z), exp2f(s[3] + lr.w))};
      *reinterpret_cast<u32x2*>(&P[0][16 * m + l15][16 * wid + 4 * g]) = pw;
    }
  }
  __syncthreads();

  for (int step = 0; step < 64; ++step) {
    int buf = step & 1;
    int jg = step * 64;
    int jn = (step < 63) ? jg + 64 : jg;
    // prefetch next K A-frags
    const u16* krn = kb + (size_t)(jn + 16 * wid + l15) * 64;
    bf16x8 nk0 = ld8(krn + 8 * g);
    bf16x8 nk1 = ld8(krn + 32 + 8 * g);
    // V B-frags for this step
    bf16x8 bv[2][2];
#pragma unroll
    for (int n = 0; n < 2; ++n)
#pragma unroll
      for (int h = 0; h < 2; ++h)
        bv[n][h] = ld8(vb + (size_t)(32 * wid + 16 * n + l15) * 4096 + jg + h * 32 + 8 * g);
    // PV from P[buf]
#pragma unroll
    for (int h = 0; h < 2; ++h) {
      bf16x8 ap[4];
#pragma unroll
      for (int m = 0; m < 4; ++m)
        ap[m] = ld8(&P[buf][16 * m + l15][h * 32 + 8 * g]);
#pragma unroll
      for (int n = 0; n < 2; ++n)
#pragma unroll
        for (int m = 0; m < 4; ++m) oacc[m][n] = MFMA16(ap[m], bv[n][h], oacc[m][n]);
    }
    // S(step+1) -> P[1-buf]
    if (step < 63) {
      float4 lr = *reinterpret_cast<const float4*>(&lrsL[jn + 16 * wid + 4 * g]);
#pragma unroll
      for (int m = 0; m < 4; ++m) {
        f32x4 s = fz4();
        s = MFMA16(nk0, aq[m][0], s);
        s = MFMA16(nk1, aq[m][1], s);
        u32x2 pw = {pack2(exp2f(s[0] + lr.x), exp2f(s[1] + lr.y)),
                    pack2(exp2f(s[2] + lr.z), exp2f(s[3] + lr.w))};
        *reinterpret_cast<u32x2*>(&P[1 - buf][16 * m + l15][16 * wid + 4 * g]) = pw;
      }
    }
    __syncthreads();
  }
#pragma unroll
  for (int m = 0; m < 4; ++m)
#pragma unroll
    for (int n = 0; n < 2; ++n) {
      int c = cc * 128 + 32 * wid + 16 * n + l15;
#pragma unroll
      for (int r = 0; r < 4; ++r) {
        int pos = i0 + 16 * m + 4 * g + r;
        attT[((size_t)b * 4096 + pos) * 256 + c] = f2bf(oacc[m][n][r]);
      }
    }
}

// ---- fused MLP: mish(W1 att + b1) (LDS) -> W2 .. + b2 + x -----------------
// i-tile = 16 pos, grid 1024 (b = id&3). att read directly from global.
__global__ __launch_bounds__(256, 4) void k_mlp(
    const u16* __restrict__ attT, const u16* __restrict__ w1,
    const float* __restrict__ b1, const u16* __restrict__ w2,
    const float* __restrict__ b2, const float* __restrict__ x,
    float* __restrict__ out) {
  __shared__ u16 hdnS[16][264];
  int b = blockIdx.x & 3, n0 = (blockIdx.x >> 2) * 16;
  int lane = threadIdx.x & 63, wid = threadIdx.x >> 6;
  int l15 = lane & 15, g = lane >> 4;
  const u16* arow = attT + ((size_t)b * 4096 + n0) * 256;

  // stage 1: hdn = mish(att @ W1^T + b1) -> LDS
  f32x4 h4[4];
#pragma unroll
  for (int n = 0; n < 4; ++n) h4[n] = fz4();
  for (int kk = 0; kk < 8; ++kk) {
    int c0 = kk * 32 + 8 * g;
    bf16x8 am = ld8(arow + l15 * 256 + c0);
#pragma unroll
    for (int n = 0; n < 4; ++n) {
      bf16x8 bn = ld8(w1 + (64 * wid + 16 * n + l15) * 256 + c0);
      h4[n] = MFMA16(am, bn, h4[n]);
    }
  }
#pragma unroll
  for (int n = 0; n < 4; ++n) {
    int hh = 64 * wid + 16 * n + l15;
    float bb = b1[hh];
#pragma unroll
    for (int r = 0; r < 4; ++r) {
      float v = h4[n][r] + bb;
      float sp_ = (v > 15.f) ? v : __logf(1.f + __expf(v));
      float e2 = __expf(-2.f * sp_);
      float th = (1.f - e2) / (1.f + e2);
      hdnS[4 * g + r][hh] = f2bf(v * th);
    }
  }
  __syncthreads();

  // stage 2: out = hdn @ W2^T + b2 + x. A=W2 rows o, B=hdn (col=pos, k=h).
  f32x4 acc[4];
#pragma unroll
  for (int m = 0; m < 4; ++m) acc[m] = fz4();
  for (int kk = 0; kk < 8; ++kk) {
    int c0 = kk * 32 + 8 * g;
    bf16x8 bn = ld8(&hdnS[l15][c0]);
#pragma unroll
    for (int m = 0; m < 4; ++m) {
      bf16x8 am = ld8(w2 + (64 * wid + 16 * m + l15) * 256 + c0);
      acc[m] = MFMA16(am, bn, acc[m]);
    }
  }
#pragma unroll
  for (int m = 0; m < 4; ++m)
#pragma unroll
    for (int r = 0; r < 4; ++r) {
      int o = 64 * wid + 16 * m + 4 * g + r;
      int pos = n0 + l15;
      size_t idx = ((size_t)b * 256 + o) * 4096 + pos;
      out[idx] = acc[m][r] + b2[o] + x[idx];
    }
}

// ---- workspace layout (bytes) ---------------------------------------------
#define WS_QT 0u          //  2,097,152  Qt  [4][4096][64]  bf16 (pre-scaled)
#define WS_KT 2097152u    //  2,097,152  Kt  [4][4096][64]  bf16
#define WS_VC 4194304u    //  8,388,608  Vc  [4][256][4096] bf16
#define WS_SP 12582912u   //    262,144  sp  [4 ic][4 b][4096] fp32
#define WS_ATT 12845056u  //  8,388,608  attT[4][4096][256] bf16
#define WS_WQ 21233664u   //     32,768
#define WS_WK 21266432u   //     32,768
#define WS_WV 21299200u   //    131,072
#define WS_W1 21430272u   //    131,072
#define WS_W2 21561344u   //    131,072   (end: 21,692,416)

extern "C" void kernel_launch(void* const* d_in, const int* in_sizes, int n_in,
                              void* d_out, int out_size, void* d_ws, size_t ws_size,
                              hipStream_t stream) {
  (void)in_sizes; (void)n_in; (void)out_size; (void)ws_size;
  const float* x  = (const float*)d_in[0];
  const float* WQ = (const float*)d_in[1];
  const float* bQ = (const float*)d_in[2];
  const float* WK = (const float*)d_in[3];
  const float* bK = (const float*)d_in[4];
  const float* WV = (const float*)d_in[5];
  const float* bV = (const float*)d_in[6];
  const float* PE = (const float*)d_in[7];
  const float* W1 = (const float*)d_in[8];
  const float* b1 = (const float*)d_in[9];
  const float* W2 = (const float*)d_in[10];
  const float* b2 = (const float*)d_in[11];
  float* out = (float*)d_out;
  char* ws = (char*)d_ws;

  u16* Qt   = (u16*)(ws + WS_QT);
  u16* Kt   = (u16*)(ws + WS_KT);
  u16* Vc   = (u16*)(ws + WS_VC);
  float* sp = (float*)(ws + WS_SP);
  u16* attT = (u16*)(ws + WS_ATT);
  u16* wqB  = (u16*)(ws + WS_WQ);
  u16* wkB  = (u16*)(ws + WS_WK);
  u16* wvB  = (u16*)(ws + WS_WV);
  u16* w1B  = (u16*)(ws + WS_W1);
  u16* w2B  = (u16*)(ws + WS_W2);

  k_convert<<<896, 256, 0, stream>>>(WQ, WK, WV, W1, W2, wqB, wkB, wvB, w1B, w2B);
  k_proj<<<1024, 256, 0, stream>>>(x, wqB, bQ, wkB, bK, wvB, bV, PE, Qt, Kt, Vc);
  k_colsum<<<1024, 256, 0, stream>>>(Qt, Kt, sp);
  k_attn<<<512, 256, 0, stream>>>(Qt, Kt, Vc, sp, attT);
  k_mlp<<<1024, 256, 0, stream>>>(attT, w1B, b1, w2B, b2, x, out);
}